// Round 9
// baseline (535.721 us; speedup 1.0000x reference)
//
#include <hip/hip_runtime.h>

// Problem constants (from reference): x is (B, C, H, W) fp32.
constexpr int Bn = 32;
constexpr int Cn = 256;
constexpr int Hn = 96;
constexpr int Wn = 48;
constexpr int Nn = Hn * Wn;       // 4608 spatial positions
constexpr int N4 = Nn / 4;        // 1152 float4 per (b,c) row
constexpr int P  = 8;             // float4 positions per tile
constexpr int TILES = N4 / P;     // 144 tiles per batch
constexpr int NBLK  = Bn * TILES; // 4608 blocks
constexpr float BN_EPS = 1e-5f;

// native 4-float vector (HIP_vector_type is not accepted by the
// nontemporal builtins; identical 16B layout/alignment)
typedef float floatx4 __attribute__((ext_vector_type(4)));

// ---------------------------------------------------------------------------
// Fused kernel, per-batch decoupled sync, SPILL-FREE (r8 lesson: holding the
// x-tile in registers across the sync spilled to scratch -> 4x regression).
//   Grid = 4608 blocks x 256 threads. Block owns (b, tile of 8 float4).
//   Thread: pos = tid&7, grp = tid>>3 (8 channels each).
//
//   Phase A: stream the 32KB x-tile (8 loads in flight, then discard),
//            compute g/theta/phi dots; theta -> LDS; per-tile phi.g
//            partial -> relaxed atomic store + release counter increment.
//   Sync:    tid0 spins (relaxed + s_sleep) until counter[b]==144, then one
//            acquire load (invalidates L1/L2 only — L3 keeps the x tile).
//   Phase B: s = sum(144 partials)/N in fixed order (deterministic);
//            re-read the x tile (L3-hot), out = x + (theta*s)*a[c] + d[c],
//            non-temporal stores.
//
//   Read phase of later batches overlaps write phase of earlier batches.
//   No per-thread state over the sync except accumulators (~70 VGPR).
// ---------------------------------------------------------------------------
__global__ __launch_bounds__(256, 4) void fused_kernel(
    const float* __restrict__ x,
    const float* __restrict__ g_w, const float* __restrict__ g_b,
    const float* __restrict__ theta_w, const float* __restrict__ theta_b,
    const float* __restrict__ phi_w, const float* __restrict__ phi_b,
    const float* __restrict__ W_w, const float* __restrict__ W_b,
    const float* __restrict__ bn_gamma, const float* __restrict__ bn_beta,
    const float* __restrict__ bn_mean, const float* __restrict__ bn_var,
    int*   __restrict__ counters,    // B ints, zeroed each call
    float* __restrict__ part_buf,    // B * 144 floats
    float* __restrict__ out)
{
    __shared__ float wg[Cn], wt[Cn], wp[Cn];
    __shared__ float a_sh[Cn], d_sh[Cn];
    __shared__ float4 red_g[3][P], red_t[3][P], red_p[3][P]; // waves 1..3
    __shared__ float4 theta_sh[P];
    __shared__ float part_sh[TILES];
    __shared__ float part2_sh[16];
    __shared__ float s_sh;

    const int tid  = threadIdx.x;
    const int lane = tid & 63;
    const int wave = tid >> 6;
    const int pos  = tid & 7;         // n4 within tile
    const int grp  = tid >> 3;        // 0..31, 8 channels each
    const int c0   = grp * 8;

    const int bx   = blockIdx.x;
    const int b    = bx / TILES;
    const int tile = bx - b * TILES;
    const int n4   = tile * P + pos;  // 0..1151

    // stage weights + per-channel epilogue scalars
    wg[tid] = g_w[tid];
    wt[tid] = theta_w[tid];
    wp[tid] = phi_w[tid];
    {
        const float inv_std = bn_gamma[tid] * rsqrtf(bn_var[tid] + BN_EPS);
        a_sh[tid] = W_w[tid] * inv_std;
        d_sh[tid] = fmaf(W_b[tid] - bn_mean[tid], inv_std, bn_beta[tid]);
    }
    __syncthreads();

    const float4* xb = reinterpret_cast<const float4*>(x)
                     + (size_t)b * (size_t)(Cn * N4) + n4;

    // ---- Phase A: stream tile, 8 loads in flight, then accumulate ---------
    float4 ag = {0.f, 0.f, 0.f, 0.f};
    float4 at = {0.f, 0.f, 0.f, 0.f};
    float4 ap = {0.f, 0.f, 0.f, 0.f};
    {
        float4 buf[8];
        #pragma unroll
        for (int i = 0; i < 8; ++i)
            buf[i] = xb[(size_t)(c0 + i) * N4];
        #pragma unroll
        for (int i = 0; i < 8; ++i) {
            const int c = c0 + i;
            const float cg = wg[c], ct = wt[c], cp = wp[c];
            const float4 xv = buf[i];
            ag.x = fmaf(cg, xv.x, ag.x);
            ag.y = fmaf(cg, xv.y, ag.y);
            ag.z = fmaf(cg, xv.z, ag.z);
            ag.w = fmaf(cg, xv.w, ag.w);
            at.x = fmaf(ct, xv.x, at.x);
            at.y = fmaf(ct, xv.y, at.y);
            at.z = fmaf(ct, xv.z, at.z);
            at.w = fmaf(ct, xv.w, at.w);
            ap.x = fmaf(cp, xv.x, ap.x);
            ap.y = fmaf(cp, xv.y, ap.y);
            ap.z = fmaf(cp, xv.z, ap.z);
            ap.w = fmaf(cp, xv.w, ap.w);
        }
    }

    // reduce the wave's 8 grps (same pos): ^8, ^16, ^32
    #pragma unroll
    for (int m = 8; m <= 32; m <<= 1) {
        ag.x += __shfl_xor(ag.x, m); ag.y += __shfl_xor(ag.y, m);
        ag.z += __shfl_xor(ag.z, m); ag.w += __shfl_xor(ag.w, m);
        at.x += __shfl_xor(at.x, m); at.y += __shfl_xor(at.y, m);
        at.z += __shfl_xor(at.z, m); at.w += __shfl_xor(at.w, m);
        ap.x += __shfl_xor(ap.x, m); ap.y += __shfl_xor(ap.y, m);
        ap.z += __shfl_xor(ap.z, m); ap.w += __shfl_xor(ap.w, m);
    }

    if (wave > 0 && lane < P) {
        red_g[wave - 1][pos] = ag;
        red_t[wave - 1][pos] = at;
        red_p[wave - 1][pos] = ap;
    }
    __syncthreads();

    if (wave == 0 && lane < P) {
        float4 sg = ag, st = at, sp = ap;
        #pragma unroll
        for (int w = 0; w < 3; ++w) {
            const float4 rg = red_g[w][pos];
            const float4 rt = red_t[w][pos];
            const float4 rp = red_p[w][pos];
            sg.x += rg.x; sg.y += rg.y; sg.z += rg.z; sg.w += rg.w;
            st.x += rt.x; st.y += rt.y; st.z += rt.z; st.w += rt.w;
            sp.x += rp.x; sp.y += rp.y; sp.z += rp.z; sp.w += rp.w;
        }

        const float gb = g_b[0], tb = theta_b[0], pb = phi_b[0];

        float4 th;
        th.x = st.x + tb; th.y = st.y + tb; th.z = st.z + tb; th.w = st.w + tb;
        theta_sh[pos] = th;      // stays in LDS

        float p = (sg.x + gb) * (sp.x + pb)
                + (sg.y + gb) * (sp.y + pb)
                + (sg.z + gb) * (sp.z + pb)
                + (sg.w + gb) * (sp.w + pb);

        // reduce the 8 pos lanes (fixed order, deterministic)
        p += __shfl_down(p, 4);
        p += __shfl_down(p, 2);
        p += __shfl_down(p, 1);

        if (pos == 0) {
            __hip_atomic_store(&part_buf[b * TILES + tile], p,
                               __ATOMIC_RELAXED, __HIP_MEMORY_SCOPE_AGENT);
            __hip_atomic_fetch_add(&counters[b], 1,
                                   __ATOMIC_RELEASE, __HIP_MEMORY_SCOPE_AGENT);
        }
    }

    // ---- per-batch decoupled sync -----------------------------------------
    if (tid == 0) {
        while (__hip_atomic_load(&counters[b], __ATOMIC_RELAXED,
                                 __HIP_MEMORY_SCOPE_AGENT) < TILES)
            __builtin_amdgcn_s_sleep(8);
        (void)__hip_atomic_load(&counters[b], __ATOMIC_ACQUIRE,
                                __HIP_MEMORY_SCOPE_AGENT);
    }
    __syncthreads();

    // ---- Phase B: deterministic s reduction -------------------------------
    if (tid < TILES)
        part_sh[tid] = __hip_atomic_load(&part_buf[b * TILES + tid],
                                         __ATOMIC_RELAXED,
                                         __HIP_MEMORY_SCOPE_AGENT);
    __syncthreads();
    if (tid < 16) {            // 144 = 16 x 9, fixed serial order per lane
        float q = 0.f;
        #pragma unroll
        for (int k = 0; k < 9; ++k)
            q += part_sh[tid * 9 + k];
        part2_sh[tid] = q;
    }
    __syncthreads();
    if (tid == 0) {
        float q = 0.f;
        #pragma unroll
        for (int k = 0; k < 16; ++k)
            q += part2_sh[k];
        s_sh = q * (1.0f / (float)Nn);
    }
    __syncthreads();
    const float sb = s_sh;

    // ---- epilogue: re-read tile (L3-hot), nt-store out --------------------
    const float4 th = theta_sh[pos];
    const float tsx = th.x * sb, tsy = th.y * sb,
                tsz = th.z * sb, tsw = th.w * sb;

    floatx4* ob = reinterpret_cast<floatx4*>(out)
                + (size_t)b * (size_t)(Cn * N4) + n4;

    {
        float4 buf[8];
        #pragma unroll
        for (int i = 0; i < 8; ++i)
            buf[i] = xb[(size_t)(c0 + i) * N4];
        #pragma unroll
        for (int i = 0; i < 8; ++i) {
            const int c = c0 + i;
            const float a = a_sh[c];
            const float d = d_sh[c];
            const float4 xv = buf[i];

            floatx4 o;
            o.x = fmaf(tsx, a, d) + xv.x;
            o.y = fmaf(tsy, a, d) + xv.y;
            o.z = fmaf(tsz, a, d) + xv.z;
            o.w = fmaf(tsw, a, d) + xv.w;

            __builtin_nontemporal_store(o, &ob[(size_t)c * N4]);
        }
    }
}

extern "C" void kernel_launch(void* const* d_in, const int* in_sizes, int n_in,
                              void* d_out, int out_size, void* d_ws, size_t ws_size,
                              hipStream_t stream) {
    const float* x        = (const float*)d_in[0];
    const float* g_w      = (const float*)d_in[1];
    const float* g_b      = (const float*)d_in[2];
    const float* theta_w  = (const float*)d_in[3];
    const float* theta_b  = (const float*)d_in[4];
    const float* phi_w    = (const float*)d_in[5];
    const float* phi_b    = (const float*)d_in[6];
    const float* W_w      = (const float*)d_in[7];
    const float* W_b      = (const float*)d_in[8];
    const float* bn_gamma = (const float*)d_in[9];
    const float* bn_beta  = (const float*)d_in[10];
    const float* bn_mean  = (const float*)d_in[11];
    const float* bn_var   = (const float*)d_in[12];

    float* out = (float*)d_out;

    // Workspace: counters (32 ints) at 0; partials (B*144 floats) at +512 B
    int*   counters = (int*)d_ws;
    float* part_buf = (float*)((char*)d_ws + 512);

    // counters must be zero at the start of every call (ws is not re-poisoned)
    hipMemsetAsync(counters, 0, Bn * sizeof(int), stream);

    fused_kernel<<<NBLK, 256, 0, stream>>>(
        x, g_w, g_b, theta_w, theta_b, phi_w, phi_b, W_w, W_b,
        bn_gamma, bn_beta, bn_mean, bn_var, counters, part_buf, out);
}

// Round 10
// 73.528 us; speedup vs baseline: 7.2859x; 7.2859x over previous
//
#include <hip/hip_runtime.h>

// Problem constants (from reference): x is (B, C, H, W) fp32.
constexpr int Bn = 32;
constexpr int Cn = 256;
constexpr int Hn = 96;
constexpr int Wn = 48;
constexpr int Nn = Hn * Wn;       // 4608 spatial positions
constexpr int N4 = Nn / 4;        // 1152 float4 per (b,c) row
constexpr int TILES = 72;         // 16-float4 tiles per batch (72*16 = 1152)
constexpr int TPB   = 3;          // tiles per block
constexpr int NBLK  = Bn * TILES / TPB;  // 768 blocks = exactly 3 per CU
constexpr int BPB   = TILES / TPB;       // 24 blocks per batch (72%3==0)
constexpr float BN_EPS = 1e-5f;

// native 4-float vector (HIP_vector_type is not accepted by the
// nontemporal builtins; identical 16B layout/alignment)
typedef float floatx4 __attribute__((ext_vector_type(4)));

// ---------------------------------------------------------------------------
// Pass 1: g/theta/phi channel dots. Persistent-style: 768 blocks x 256 thr
//   (exactly 3 blocks/CU, 12 waves/CU), each block owns 3 CONSECUTIVE tiles
//   of the same batch (72%3==0 -> no batch crossing). Weights staged ONCE
//   per block; reduction tail of tile t overlaps loads of tile t+1.
//   Thread: pos = tid&15 (float4 within tile), grp = tid>>4 (16 channels).
//   theta -> ws; per-tile phi.g partial -> ws (fixed-order, no atomics).
// ---------------------------------------------------------------------------
__global__ __launch_bounds__(256) void pass1_kernel(
    const float* __restrict__ x,
    const float* __restrict__ g_w, const float* __restrict__ g_b,
    const float* __restrict__ theta_w, const float* __restrict__ theta_b,
    const float* __restrict__ phi_w, const float* __restrict__ phi_b,
    float* __restrict__ theta_out,   // B * N floats
    float* __restrict__ part_out)    // B * 72 floats
{
    __shared__ float wg[Cn], wt[Cn], wp[Cn];
    __shared__ float4 red_g[3][16], red_t[3][16], red_p[3][16]; // waves 1..3

    const int tid  = threadIdx.x;
    const int lane = tid & 63;
    const int wave = tid >> 6;
    const int pos  = tid & 15;
    const int grp  = tid >> 4;        // 0..15, 16 channels each
    const int c0   = grp * 16;

    wg[tid] = g_w[tid];
    wt[tid] = theta_w[tid];
    wp[tid] = phi_w[tid];
    __syncthreads();

    const int bx    = blockIdx.x;
    const int b     = bx / BPB;
    const int tile0 = (bx - b * BPB) * TPB;

    const float gb = g_b[0], tb = theta_b[0], pb = phi_b[0];

    const float4* xbase = reinterpret_cast<const float4*>(x)
                        + (size_t)b * (size_t)(Cn * N4);

    for (int t = 0; t < TPB; ++t) {
        const int tile = tile0 + t;
        const int n4   = tile * 16 + pos;
        const float4* xb = xbase + n4;

        float4 ag = {0.f, 0.f, 0.f, 0.f};
        float4 at = {0.f, 0.f, 0.f, 0.f};
        float4 ap = {0.f, 0.f, 0.f, 0.f};

        #pragma unroll
        for (int k = 0; k < 16; k += 8) {
            float4 buf[8];
            #pragma unroll
            for (int i = 0; i < 8; ++i)
                buf[i] = xb[(size_t)(c0 + k + i) * N4];
            #pragma unroll
            for (int i = 0; i < 8; ++i) {
                const int c = c0 + k + i;
                const float cg = wg[c], ct = wt[c], cp = wp[c];
                const float4 xv = buf[i];
                ag.x = fmaf(cg, xv.x, ag.x);
                ag.y = fmaf(cg, xv.y, ag.y);
                ag.z = fmaf(cg, xv.z, ag.z);
                ag.w = fmaf(cg, xv.w, ag.w);
                at.x = fmaf(ct, xv.x, at.x);
                at.y = fmaf(ct, xv.y, at.y);
                at.z = fmaf(ct, xv.z, at.z);
                at.w = fmaf(ct, xv.w, at.w);
                ap.x = fmaf(cp, xv.x, ap.x);
                ap.y = fmaf(cp, xv.y, ap.y);
                ap.z = fmaf(cp, xv.z, ap.z);
                ap.w = fmaf(cp, xv.w, ap.w);
            }
        }

        // combine the wave's 4 grps (same pos): ^16 then ^32
        #pragma unroll
        for (int m = 16; m <= 32; m <<= 1) {
            ag.x += __shfl_xor(ag.x, m); ag.y += __shfl_xor(ag.y, m);
            ag.z += __shfl_xor(ag.z, m); ag.w += __shfl_xor(ag.w, m);
            at.x += __shfl_xor(at.x, m); at.y += __shfl_xor(at.y, m);
            at.z += __shfl_xor(at.z, m); at.w += __shfl_xor(at.w, m);
            ap.x += __shfl_xor(ap.x, m); ap.y += __shfl_xor(ap.y, m);
            ap.z += __shfl_xor(ap.z, m); ap.w += __shfl_xor(ap.w, m);
        }

        if (wave > 0 && lane < 16) {
            red_g[wave - 1][pos] = ag;
            red_t[wave - 1][pos] = at;
            red_p[wave - 1][pos] = ap;
        }
        __syncthreads();

        if (wave == 0 && lane < 16) {
            float4 sg = ag, st = at, sp = ap;
            #pragma unroll
            for (int w = 0; w < 3; ++w) {
                const float4 rg = red_g[w][pos];
                const float4 rt = red_t[w][pos];
                const float4 rp = red_p[w][pos];
                sg.x += rg.x; sg.y += rg.y; sg.z += rg.z; sg.w += rg.w;
                st.x += rt.x; st.y += rt.y; st.z += rt.z; st.w += rt.w;
                sp.x += rp.x; sp.y += rp.y; sp.z += rp.z; sp.w += rp.w;
            }

            float4 th;
            th.x = st.x + tb; th.y = st.y + tb;
            th.z = st.z + tb; th.w = st.w + tb;
            reinterpret_cast<float4*>(theta_out)[(size_t)b * N4 + n4] = th;

            float p = (sg.x + gb) * (sp.x + pb)
                    + (sg.y + gb) * (sp.y + pb)
                    + (sg.z + gb) * (sp.z + pb)
                    + (sg.w + gb) * (sp.w + pb);

            // reduce the 16 pos lanes (fixed order, deterministic)
            p += __shfl_down(p, 8);
            p += __shfl_down(p, 4);
            p += __shfl_down(p, 2);
            p += __shfl_down(p, 1);

            if (pos == 0)
                part_out[b * TILES + tile] = p;
        }
        __syncthreads();   // red_* reused next tile
    }
}

// ---------------------------------------------------------------------------
// Pass 2: elementwise epilogue. Same persistent tiling: 768 blocks x 256 thr,
//   3 consecutive tiles, one batch per block -> s computed ONCE per block,
//   a/d staged ONCE. out = x + (theta*s)*a[c] + d[c], non-temporal stores.
// ---------------------------------------------------------------------------
__global__ __launch_bounds__(256) void pass2_kernel(
    const float* __restrict__ x,
    const float* __restrict__ theta_buf,
    const float* __restrict__ part_buf,
    const float* __restrict__ W_w, const float* __restrict__ W_b,
    const float* __restrict__ bn_gamma, const float* __restrict__ bn_beta,
    const float* __restrict__ bn_mean, const float* __restrict__ bn_var,
    float* __restrict__ out)
{
    __shared__ float a_sh[Cn], d_sh[Cn];
    __shared__ float s_sh;

    const int tid = threadIdx.x;
    const int pos = tid & 15;
    const int grp = tid >> 4;         // 0..15, 16 channels each
    const int c0  = grp * 16;

    const int bx    = blockIdx.x;
    const int b     = bx / BPB;
    const int tile0 = (bx - b * BPB) * TPB;

    // stage per-channel epilogue scalars (once per block)
    {
        const float inv_std = bn_gamma[tid] * rsqrtf(bn_var[tid] + BN_EPS);
        a_sh[tid] = W_w[tid] * inv_std;
        d_sh[tid] = fmaf(W_b[tid] - bn_mean[tid], inv_std, bn_beta[tid]);
    }

    // s reduction (once per block): 72 partials, fixed-order tree
    if (tid < 64) {
        float p = part_buf[b * TILES + tid];
        if (tid < TILES - 64)
            p += part_buf[b * TILES + 64 + tid];
        p += __shfl_down(p, 32);
        p += __shfl_down(p, 16);
        p += __shfl_down(p, 8);
        p += __shfl_down(p, 4);
        p += __shfl_down(p, 2);
        p += __shfl_down(p, 1);
        if (tid == 0) s_sh = p * (1.0f / (float)Nn);
    }
    __syncthreads();
    const float sb = s_sh;

    const float4* xbase = reinterpret_cast<const float4*>(x)
                        + (size_t)b * (size_t)(Cn * N4);
    floatx4* obase = reinterpret_cast<floatx4*>(out)
                   + (size_t)b * (size_t)(Cn * N4);

    for (int t = 0; t < TPB; ++t) {
        const int tile = tile0 + t;
        const int n4   = tile * 16 + pos;

        const float4 th = reinterpret_cast<const float4*>(theta_buf)[(size_t)b * N4 + n4];
        const float tsx = th.x * sb, tsy = th.y * sb,
                    tsz = th.z * sb, tsw = th.w * sb;

        const float4* xb = xbase + n4;
        floatx4*      ob = obase + n4;

        #pragma unroll
        for (int k = 0; k < 16; k += 8) {
            float4 buf[8];
            #pragma unroll
            for (int i = 0; i < 8; ++i)
                buf[i] = xb[(size_t)(c0 + k + i) * N4];
            #pragma unroll
            for (int i = 0; i < 8; ++i) {
                const int c = c0 + k + i;
                const float a = a_sh[c];
                const float d = d_sh[c];
                const float4 xv = buf[i];

                floatx4 o;
                o.x = fmaf(tsx, a, d) + xv.x;
                o.y = fmaf(tsy, a, d) + xv.y;
                o.z = fmaf(tsz, a, d) + xv.z;
                o.w = fmaf(tsw, a, d) + xv.w;

                __builtin_nontemporal_store(o, &ob[(size_t)c * N4]);
            }
        }
    }
}

extern "C" void kernel_launch(void* const* d_in, const int* in_sizes, int n_in,
                              void* d_out, int out_size, void* d_ws, size_t ws_size,
                              hipStream_t stream) {
    const float* x        = (const float*)d_in[0];
    const float* g_w      = (const float*)d_in[1];
    const float* g_b      = (const float*)d_in[2];
    const float* theta_w  = (const float*)d_in[3];
    const float* theta_b  = (const float*)d_in[4];
    const float* phi_w    = (const float*)d_in[5];
    const float* phi_b    = (const float*)d_in[6];
    const float* W_w      = (const float*)d_in[7];
    const float* W_b      = (const float*)d_in[8];
    const float* bn_gamma = (const float*)d_in[9];
    const float* bn_beta  = (const float*)d_in[10];
    const float* bn_mean  = (const float*)d_in[11];
    const float* bn_var   = (const float*)d_in[12];

    float* out = (float*)d_out;

    // Workspace: partials (2304 floats) at 0; theta (B*N floats) at +16 KiB
    float* part_buf  = (float*)d_ws;
    float* theta_buf = (float*)((char*)d_ws + 16384);

    pass1_kernel<<<NBLK, 256, 0, stream>>>(
        x, g_w, g_b, theta_w, theta_b, phi_w, phi_b, theta_buf, part_buf);

    pass2_kernel<<<NBLK, 256, 0, stream>>>(
        x, theta_buf, part_buf, W_w, W_b,
        bn_gamma, bn_beta, bn_mean, bn_var, out);
}